// Round 13
// baseline (190.665 us; speedup 1.0000x reference)
//
#include <hip/hip_runtime.h>
#include <hip/hip_fp16.h>

#define LRELU_SLOPE 0.2f

typedef _Float16 f16x8 __attribute__((ext_vector_type(8)));
typedef _Float16 f16x2 __attribute__((ext_vector_type(2)));
typedef float    f32x4 __attribute__((ext_vector_type(4)));

// ---------------- DPP helpers ----------------
template <int CTRL>
__device__ __forceinline__ float dpp_add(float x) {
    int xi = __float_as_int(x);
    int yi = __builtin_amdgcn_update_dpp(xi, xi, CTRL, 0xF, 0xF, false);
    return x + __int_as_float(yi);
}
__device__ __forceinline__ float reduce16(float t) {
    t = dpp_add<0x128>(t);  // row_ror:8  (row = 16 lanes)
    t = dpp_add<0x124>(t);  // row_ror:4
    t = dpp_add<0x122>(t);  // row_ror:2
    t = dpp_add<0x121>(t);  // row_ror:1
    return t;
}
__device__ __forceinline__ float reduce_quad(float t) {
    t = dpp_add<0xB1>(t);   // quad_perm [1,0,3,2]
    t = dpp_add<0x4E>(t);   // quad_perm [2,3,0,1]
    return t;
}

__device__ __forceinline__ f16x2 u32_to_h2(unsigned u) {
    union { unsigned u; f16x2 h; } cv; cv.u = u; return cv.h;
}

// ---------------- block-wide exclusive scan (NW waves) ----------------------
template <int NW>
__device__ __forceinline__ int block_excl_scan_t(int v) {
    __shared__ int wsum[NW];
    int tid = threadIdx.x;
    int lane = tid & 63;
    int wid  = tid >> 6;
    int x = v;
#pragma unroll
    for (int off = 1; off < 64; off <<= 1) {
        int y = __shfl_up(x, off, 64);
        if (lane >= off) x += y;
    }
    if (lane == 63) wsum[wid] = x;
    __syncthreads();
    int wofs = 0;
#pragma unroll
    for (int i = 0; i < NW; ++i)
        if (i < wid) wofs += wsum[i];
    return wofs + x - v;  // exclusive
}

// role split for fused kernels: interleave A/B blocks by parity
__device__ __forceinline__ void role_split(int bid, int gA, int gB, bool& isA, int& idx) {
    int m = (gA < gB ? gA : gB) * 2;
    if (bid < m) { isA = (bid & 1) == 0; idx = bid >> 1; }
    else         { isA = (gA > gB);      idx = (m >> 1) + (bid - m); }
}

// ---------------- D0: weight prep ----------------
// Fused L0 weights (Win@Ws0 / Win@Wd0) and L1 weights, fp16 hi/lo Markidis
// split, stored in MFMA-fragment-coalesced layout:
//   addr(m2,t2,ks,lk,lr,e) = group(m2,t2,ks)*512 + lk*128 + lr*8 + e
// wq : [part(2)][32 groups][512]  halfs (64 KB), groups = (m2*4+t2)*4+ks (K=128)
// wq1: [part(2)][16 groups][512]  halfs (32 KB), groups = (m2*4+t2)*2+ks (K=64)
// bf0: fused layer-0 biases: [0..63]=bin@Ws0+bs0, [64..127]=bin@Wd0+bd0
__global__ __launch_bounds__(128) void k_prep(
        const float* __restrict__ Win, const float* __restrict__ bin,
        const float* __restrict__ Ws0, const float* __restrict__ bs0,
        const float* __restrict__ Wd0, const float* __restrict__ bd0,
        const float* __restrict__ Ws1, const float* __restrict__ Wd1,
        __half* __restrict__ wq, __half* __restrict__ wq1,
        float* __restrict__ bf0) {
    _Float16* w0 = (_Float16*)wq;
    _Float16* w1 = (_Float16*)wq1;
    int b = blockIdx.x, t = threadIdx.x;
    int m = t >> 6;      // 0 = src-mat, 1 = dst-mat
    int c = t & 63;      // output column
    int t2 = c >> 4, lr = c & 15;
    if (b < 128) {       // fused layer-0, k-row = b
        const float* W0 = m ? Wd0 : Ws0;
        float s = 0.f;
#pragma unroll 8
        for (int k = 0; k < 64; ++k) s = fmaf(Win[b * 64 + k], W0[k * 64 + c], s);
        _Float16 hi = (_Float16)s;
        _Float16 lo = (_Float16)(s - (float)hi);
        int ks = b >> 5, lk = (b >> 3) & 3, e = b & 7;
        int idx = (((m * 4 + t2) * 4 + ks) * 4 + lk) * 128 + lr * 8 + e;
        w0[idx]         = hi;
        w0[16384 + idx] = lo;
    } else if (b < 192) { // layer-1, k-row = b-128
        int r = b - 128;
        const float* W1 = m ? Wd1 : Ws1;
        float v = W1[r * 64 + c];
        _Float16 hi = (_Float16)v;
        _Float16 lo = (_Float16)(v - (float)hi);
        int ks = r >> 5, lk = (r >> 3) & 3, e = r & 7;
        int idx = (((m * 4 + t2) * 2 + ks) * 4 + lk) * 128 + lr * 8 + e;
        w1[idx]        = hi;
        w1[8192 + idx] = lo;
    } else {              // b == 192: fused biases
        const float* W0 = m ? Wd0 : Ws0;
        const float* b0 = m ? bd0 : bs0;
        float s = b0[c];
#pragma unroll 8
        for (int k = 0; k < 64; ++k) s = fmaf(bin[k], W0[k * 64 + c], s);
        bf0[m * 64 + c] = s;
    }
}

// ---------------- D1: hist  ||  MFMA fs0/fd0 (fused weights, K=128) ----------
// fd stored FP16 (it is consumed in fp16 packed math downstream).
__global__ __launch_bounds__(256) void k_p1_fused(
        const int* __restrict__ dst, int* __restrict__ counts_T, int E, int B1, int NB,
        const float* __restrict__ feat,
        const __half* __restrict__ wq, const float* __restrict__ bf0,
        __half* __restrict__ fs_h, __half* __restrict__ fd, int n, int g_gemm) {
    __shared__ int hist[256];
    bool isA; int idx;
    role_split(blockIdx.x, B1, g_gemm, isA, idx);
    if (isA) {
        hist[threadIdx.x] = 0;
        __syncthreads();
        int base = idx * 4096;
        if (base + 4096 <= E) {
            const int4* d4 = (const int4*)(dst + base);
#pragma unroll
            for (int it = 0; it < 4; ++it) {
                int4 q = d4[it * 256 + threadIdx.x];
                atomicAdd(&hist[q.x >> 8], 1);
                atomicAdd(&hist[q.y >> 8], 1);
                atomicAdd(&hist[q.z >> 8], 1);
                atomicAdd(&hist[q.w >> 8], 1);
            }
        } else {
            for (int it = 0; it < 16; ++it) {
                int e = base + it * 256 + threadIdx.x;
                if (e < E) atomicAdd(&hist[dst[e] >> 8], 1);
            }
        }
        __syncthreads();
        if (threadIdx.x < NB) counts_T[threadIdx.x * B1 + idx] = hist[threadIdx.x];
        return;
    }
    const _Float16* w = (const _Float16*)wq;
    int node0 = idx * 64;
    int wv   = threadIdx.x >> 6;
    int lane = threadIdx.x & 63;
    int lr = lane & 15;   // A-row / B-col in tile
    int lk = lane >> 4;   // k-chunk selector
    int lofs = lk * 128 + lr * 8;   // lane offset within B fragment group
    int arow = node0 + wv * 16 + lr;
    int arc  = arow < n ? arow : n - 1;
    const float* fp = feat + (size_t)arc * 128 + lk * 8;
    f32x4 zero = {0.f, 0.f, 0.f, 0.f};
    f32x4 acc[2][4];
#pragma unroll
    for (int m2 = 0; m2 < 2; ++m2)
#pragma unroll
        for (int t2 = 0; t2 < 4; ++t2) acc[m2][t2] = zero;
#pragma unroll
    for (int ks = 0; ks < 4; ++ks) {   // K = 128, 32 per step
        float4 a0 = *(const float4*)(fp + ks * 32);
        float4 a1 = *(const float4*)(fp + ks * 32 + 4);
        float av[8] = {a0.x, a0.y, a0.z, a0.w, a1.x, a1.y, a1.z, a1.w};
        f16x8 ahi, alo;
#pragma unroll
        for (int i = 0; i < 8; ++i) {
            _Float16 hh = (_Float16)av[i];
            ahi[i] = hh;
            alo[i] = (_Float16)(av[i] - (float)hh);
        }
#pragma unroll
        for (int m2 = 0; m2 < 2; ++m2) {
#pragma unroll
            for (int t2 = 0; t2 < 4; ++t2) {
                const _Float16* wb = w + ((m2 * 4 + t2) * 4 + ks) * 512 + lofs;
                f16x8 bhi = *(const f16x8*)(wb);
                f16x8 blo = *(const f16x8*)(wb + 16384);
                acc[m2][t2] = __builtin_amdgcn_mfma_f32_16x16x32_f16(ahi, bhi, acc[m2][t2], 0, 0, 0);
                acc[m2][t2] = __builtin_amdgcn_mfma_f32_16x16x32_f16(alo, bhi, acc[m2][t2], 0, 0, 0);
                acc[m2][t2] = __builtin_amdgcn_mfma_f32_16x16x32_f16(ahi, blo, acc[m2][t2], 0, 0, 0);
            }
        }
    }
    int obase = node0 + wv * 16 + lk * 4;   // D row = (lane>>4)*4 + reg
#pragma unroll
    for (int t2 = 0; t2 < 4; ++t2) {
        int col = t2 * 16 + lr;
        float bs = bf0[col];
        float bd = bf0[64 + col];
#pragma unroll
        for (int r = 0; r < 4; ++r) {
            int nd = obase + r;
            if (nd < n) {
                fs_h[(size_t)nd * 64 + col] = __float2half(acc[0][t2][r] + bs);
                fd[(size_t)nd * 64 + col]   = __float2half(acc[1][t2][r] + bd);
            }
        }
    }
}

// ---------------- D2: parallel coarse scan ----------------
__global__ __launch_bounds__(256) void k_scan(
        const int* __restrict__ counts_T, int* __restrict__ off_T,
        int* __restrict__ Ssum, int* __restrict__ row_ptr,
        int* __restrict__ edge_src, int E, int B1, int NB, int n_nodes) {
    int c = blockIdx.x * 4 + (threadIdx.x >> 6);
    int lane = threadIdx.x & 63;
    if (c < NB) {
        int carry = 0;
        for (int b0 = 0; b0 < B1; b0 += 64) {
            int b = b0 + lane;
            int v = (b < B1) ? counts_T[c * B1 + b] : 0;
            int x = v;
#pragma unroll
            for (int o = 1; o < 64; o <<= 1) {
                int y = __shfl_up(x, o, 64);
                if (lane >= o) x += y;
            }
            if (b < B1) off_T[c * B1 + b] = carry + x - v;
            carry += __shfl(x, 63, 64);
        }
        if (lane == 0) Ssum[c] = carry;
    }
    if (blockIdx.x == 0) {
        if (threadIdx.x < 64) edge_src[E + threadIdx.x] = 0;  // pad for k_agg
        if (threadIdx.x == 0) row_ptr[n_nodes] = E;
    }
}

// ---------------- D3: coarse partition, packed 24-bit (src<<8)|fine ----------
__global__ __launch_bounds__(256) void k_p3(
        const int* __restrict__ src, const int* __restrict__ dst,
        const int* __restrict__ off_T, const int* __restrict__ Ssum,
        int* __restrict__ karr, int E, int B1, int NB) {
    __shared__ int cur[256];
    int b = blockIdx.x, t = threadIdx.x;
    int v = (t < NB) ? Ssum[t] : 0;
    int base_t = block_excl_scan_t<4>(v);   // bucket_base[t]
    cur[t] = (t < NB) ? base_t + off_T[t * B1 + b] : 0;
    __syncthreads();
    int base = b * 4096;
    if (base + 4096 <= E) {
        const int4* d4 = (const int4*)(dst + base);
        const int4* s4 = (const int4*)(src + base);
#pragma unroll
        for (int it = 0; it < 4; ++it) {
            int4 qd = d4[it * 256 + t];
            int4 qs = s4[it * 256 + t];
            int pos;
            pos = atomicAdd(&cur[qd.x >> 8], 1); karr[pos] = (qs.x << 8) | (qd.x & 255);
            pos = atomicAdd(&cur[qd.y >> 8], 1); karr[pos] = (qs.y << 8) | (qd.y & 255);
            pos = atomicAdd(&cur[qd.z >> 8], 1); karr[pos] = (qs.z << 8) | (qd.z & 255);
            pos = atomicAdd(&cur[qd.w >> 8], 1); karr[pos] = (qs.w << 8) | (qd.w & 255);
        }
    } else {
        for (int it = 0; it < 16; ++it) {
            int e = base + it * 256 + t;
            if (e < E) {
                int d = dst[e], s = src[e];
                int pos = atomicAdd(&cur[d >> 8], 1);  // LDS atomic
                karr[pos] = (s << 8) | (d & 255);
            }
        }
    }
}

// ---------------- D4: fine counting sort (512 thr), single global pass -------
__global__ __launch_bounds__(512) void k_p4(
        const int* __restrict__ karr, const int* __restrict__ Ssum,
        int* __restrict__ row_ptr, int* __restrict__ edge_src, int n, int NB) {
    __shared__ int sb[257];
    __shared__ int cnt[256];
    __shared__ int curv[256];
    __shared__ int ebuf[8192];   // 32KB: bucket mean 4096, std ~64
    int c = blockIdx.x, t = threadIdx.x;
    int v = (t < NB) ? Ssum[t] : 0;
    int excl = block_excl_scan_t<8>(v);
    if (t < 256) {
        sb[t] = excl;
        if (t == 255) sb[256] = excl + v;
        cnt[t] = 0;
    }
    __syncthreads();
    int lo = sb[c], hi = sb[c + 1];
    int ec = hi - lo;
    int nbuf = ec < 8192 ? ec : 8192;
    for (int i = t; i < nbuf; i += 512) {
        int p = karr[lo + i];
        ebuf[i] = p;
        atomicAdd(&cnt[p & 255], 1);
    }
    for (int i = 8192 + t; i < ec; i += 512)      // overflow path (theoretical)
        atomicAdd(&cnt[karr[lo + i] & 255], 1);
    __syncthreads();
    int v2 = (t < 256) ? cnt[t] : 0;
    int excl2 = block_excl_scan_t<8>(v2);
    if (t < 256) {
        int node = c * 256 + t;
        if (node < n) row_ptr[node] = lo + excl2;
        curv[t] = lo + excl2;
    }
    __syncthreads();
    for (int i = t; i < nbuf; i += 512) {
        int p = ebuf[i];
        int pos = atomicAdd(&curv[p & 255], 1);   // LDS atomic
        edge_src[pos] = p >> 8;                    // top bits 0 (24-bit pack)
    }
    for (int i = 8192 + t; i < ec; i += 512) {
        int p = karr[lo + i];
        int pos = atomicAdd(&curv[p & 255], 1);
        edge_src[pos] = p >> 8;
    }
}

// ---------------- GATv2 aggregate common (packed fp16 edge math) -------------
__device__ __forceinline__ void edge_accum_pk(
        uint2 raw, f16x2 fd01, f16x2 fd23, f16x2 a01, f16x2 a23,
        f16x2 slope2, bool valid, float& ssum, float4& acc) {
    f16x2 h01 = u32_to_h2(raw.x);
    f16x2 h23 = u32_to_h2(raw.y);
    f16x2 t01 = h01 + fd01;
    f16x2 t23 = h23 + fd23;
    f16x2 l01 = __builtin_elementwise_max(t01, t01 * slope2);
    f16x2 l23 = __builtin_elementwise_max(t23, t23 * slope2);
    f16x2 s2  = l01 * a01 + l23 * a23;
    float s = (float)s2[0] + (float)s2[1];
    s = reduce_quad(s);
    float p = valid ? __expf(s) : 0.f;
    ssum += p;
    acc.x = fmaf(p, (float)h01[0], acc.x);
    acc.y = fmaf(p, (float)h01[1], acc.y);
    acc.z = fmaf(p, (float)h23[0], acc.z);
    acc.w = fmaf(p, (float)h23[1], acc.w);
}

// Software-pipelined gather-aggregate for one 16-lane slot over [s0,s1).
__device__ __forceinline__ void gather_run(
        const __half* __restrict__ fs_h, const int* __restrict__ edge_src,
        f16x2 a01, f16x2 a23, f16x2 fd01, f16x2 fd23, f16x2 slope2,
        int sl, int s0, int s1, float& ssum, float4& acc) {
    if (s0 >= s1) return;
    int id[8];
#pragma unroll
    for (int j = 0; j < 8; ++j)
        id[j] = edge_src[s0 + j];                    // pad past E is zeroed
    for (int e = s0; e < s1; e += 8) {
        uint2 raw[8];
#pragma unroll
        for (int j = 0; j < 8; ++j)
            raw[j] = *(const uint2*)(fs_h + (size_t)(unsigned)id[j] * 64 + sl * 4);
        int idn[8];
#pragma unroll
        for (int j = 0; j < 8; ++j)
            idn[j] = edge_src[e + 8 + j];            // prefetch next batch (pad-safe)
#pragma unroll
        for (int j = 0; j < 8; ++j)
            edge_accum_pk(raw[j], fd01, fd23, a01, a23, slope2,
                          e + j < s1, ssum, acc);
#pragma unroll
        for (int j = 0; j < 8; ++j) id[j] = idn[j];
    }
}

// ---------------- D5: layer-0 aggregate + layer-1 fs/fd MFMA (fused) ---------
// 512 threads. Phase A: 32 slots x 2 rounds gather-aggregate 64 nodes with
// degree-rank slot assignment. Phase B: 8 waves run layer-1 projections from
// LDS via split-fp16 MFMA. L1 outputs to separate buffers (fs1/fd1).
__global__ __launch_bounds__(512) void k_agg0_fsfd(
        const __half* __restrict__ fs_h, const uint2* __restrict__ fdh,
        const float4* __restrict__ attn4,
        const int* __restrict__ row_ptr, const int* __restrict__ edge_src,
        const __half* __restrict__ wq1,
        const float* __restrict__ bs, const float* __restrict__ bd,
        __half* __restrict__ fs1, __half* __restrict__ fd1, int n) {
    __shared__ float HL[64 * 68];
    __shared__ int dcnt[64];
    __shared__ int perm[64];
    int tid  = threadIdx.x;
    int lane = tid & 63;
    int w    = tid >> 6;        // wave 0..7
    int slot = tid >> 4;        // 0..31
    int sl   = tid & 15;
    int node0 = blockIdx.x * 64;
    if (tid < 64) {
        int node = node0 + tid;
        int cnt = 0;
        if (node < n) cnt = row_ptr[node + 1] - row_ptr[node];
        dcnt[tid] = cnt;
    }
    __syncthreads();
    if (tid < 64) {
        int mc = dcnt[tid];
        int rank = 0;
#pragma unroll 8
        for (int j = 0; j < 64; ++j) {
            int cj = dcnt[j];
            rank += ((cj > mc) || (cj == mc && j < tid)) ? 1 : 0;
        }
        perm[rank] = tid;
    }
    __syncthreads();
    float4 a4 = attn4[sl];
    f16x2 a01 = { (_Float16)a4.x, (_Float16)a4.y };
    f16x2 a23 = { (_Float16)a4.z, (_Float16)a4.w };
    f16x2 slope2 = { (_Float16)LRELU_SLOPE, (_Float16)LRELU_SLOPE };
#pragma unroll
    for (int r = 0; r < 2; ++r) {
        int li = perm[r * 32 + slot];   // degree-rank -> local node
        int node = node0 + li;
        bool act = node < n;
        int nd = act ? node : 0;
        uint2 fdr = fdh[(size_t)nd * 16 + sl];
        f16x2 fd01 = u32_to_h2(fdr.x);
        f16x2 fd23 = u32_to_h2(fdr.y);
        int s0 = row_ptr[nd];
        int s1 = act ? row_ptr[nd + 1] : s0;
        float4 acc = {0.f, 0.f, 0.f, 0.f};
        float ssum = 0.f;
        gather_run(fs_h, edge_src, a01, a23, fd01, fd23, slope2,
                   sl, s0, s1, ssum, acc);
        float inv = (s1 > s0) ? 1.f / ssum : 0.f;
        float4 o;
        o.x = fmaxf(acc.x * inv, 0.f);
        o.y = fmaxf(acc.y * inv, 0.f);
        o.z = fmaxf(acc.z * inv, 0.f);
        o.w = fmaxf(acc.w * inv, 0.f);               // inactive rows -> zeros
        *(float4*)(HL + li * 68 + sl * 4) = o;
    }
    __syncthreads();
    // ---- Phase B: layer-1 fs/fd GEMM from LDS h-tile ----
    const _Float16* wp = (const _Float16*)wq1;
    int lr = lane & 15;
    int lk = lane >> 4;
    int rg = (w & 3) * 16;      // row group
    int m2 = w >> 2;            // 0 = fs, 1 = fd
    int lofs = lk * 128 + lr * 8;
    f32x4 zero = {0.f, 0.f, 0.f, 0.f};
    f32x4 acc2[4];
#pragma unroll
    for (int t2 = 0; t2 < 4; ++t2) acc2[t2] = zero;
#pragma unroll
    for (int ks = 0; ks < 2; ++ks) {   // K = 64
        const float* hp = HL + (rg + lr) * 68 + ks * 32 + lk * 8;
        float4 a0v = *(const float4*)(hp);
        float4 a1v = *(const float4*)(hp + 4);
        float av[8] = {a0v.x, a0v.y, a0v.z, a0v.w, a1v.x, a1v.y, a1v.z, a1v.w};
        f16x8 ahi, alo;
#pragma unroll
        for (int i = 0; i < 8; ++i) {
            _Float16 hh = (_Float16)av[i];
            ahi[i] = hh;
            alo[i] = (_Float16)(av[i] - (float)hh);
        }
#pragma unroll
        for (int t2 = 0; t2 < 4; ++t2) {
            const _Float16* wb = wp + ((m2 * 4 + t2) * 2 + ks) * 512 + lofs;
            f16x8 bhi = *(const f16x8*)(wb);
            f16x8 blo = *(const f16x8*)(wb + 8192);
            acc2[t2] = __builtin_amdgcn_mfma_f32_16x16x32_f16(ahi, bhi, acc2[t2], 0, 0, 0);
            acc2[t2] = __builtin_amdgcn_mfma_f32_16x16x32_f16(alo, bhi, acc2[t2], 0, 0, 0);
            acc2[t2] = __builtin_amdgcn_mfma_f32_16x16x32_f16(ahi, blo, acc2[t2], 0, 0, 0);
        }
    }
    const float* bp = m2 ? bd : bs;
    int obase = node0 + rg + lk * 4;
#pragma unroll
    for (int t2 = 0; t2 < 4; ++t2) {
        int col = t2 * 16 + lr;
        float bv = bp[col];
#pragma unroll
        for (int r = 0; r < 4; ++r) {
            int nd = obase + r;
            if (nd < n) {
                if (m2 == 0)
                    fs1[(size_t)nd * 64 + col] = __float2half(acc2[t2][r] + bv);
                else
                    fd1[(size_t)nd * 64 + col] = __float2half(acc2[t2][r] + bv);
            }
        }
    }
}

// ---------------- D7: layer-1 aggregate + output projection ------------------
// 256 threads, 16 nodes, degree-rank slot assignment.
__global__ __launch_bounds__(256) void k_agg_out(
        const __half* __restrict__ fs_h, const uint2* __restrict__ fdh,
        const float4* __restrict__ attn4,
        const int* __restrict__ row_ptr, const int* __restrict__ edge_src,
        const float4* __restrict__ Wo4,
        const float* __restrict__ bo, float2* __restrict__ outp, int n) {
    __shared__ int dcnt[16];
    __shared__ int perm16[16];
    int t    = threadIdx.x;
    int lane = t & 63;
    int wid  = t >> 6;
    int slot = lane >> 4;
    int sl   = lane & 15;
    int node0 = blockIdx.x * 16;
    if (t < 16) {
        int node = node0 + t;
        int cnt = 0;
        if (node < n) cnt = row_ptr[node + 1] - row_ptr[node];
        dcnt[t] = cnt;
    }
    __syncthreads();
    if (t < 16) {
        int mc = dcnt[t];
        int rank = 0;
#pragma unroll
        for (int j = 0; j < 16; ++j)
            rank += ((dcnt[j] > mc) || (dcnt[j] == mc && j < t)) ? 1 : 0;
        perm16[rank] = t;
    }
    __syncthreads();
    int li = perm16[wid * 4 + slot];   // degree-rank -> local node
    int node = node0 + li;
    bool act = node < n;
    int nd = act ? node : 0;
    float4 a4  = attn4[sl];
    f16x2 a01 = { (_Float16)a4.x, (_Float16)a4.y };
    f16x2 a23 = { (_Float16)a4.z, (_Float16)a4.w };
    f16x2 slope2 = { (_Float16)LRELU_SLOPE, (_Float16)LRELU_SLOPE };
    uint2 fdr = fdh[(size_t)nd * 16 + sl];
    f16x2 fd01 = u32_to_h2(fdr.x);
    f16x2 fd23 = u32_to_h2(fdr.y);
    int s0 = row_ptr[nd];
    int s1 = act ? row_ptr[nd + 1] : s0;
    float4 acc = {0.f, 0.f, 0.f, 0.f};
    float ssum = 0.f;
    gather_run(fs_h, edge_src, a01, a23, fd01, fd23, slope2,
               sl, s0, s1, ssum, acc);
    float inv = (s1 > s0) ? 1.f / ssum : 0.f;
    float4 o;
    o.x = fmaxf(acc.x * inv, 0.f);
    o.y = fmaxf(acc.y * inv, 0.f);
    o.z = fmaxf(acc.z * inv, 0.f);
    o.w = fmaxf(acc.w * inv, 0.f);
    float4 wA = Wo4[sl * 2 + 0];
    float4 wB = Wo4[sl * 2 + 1];
    float c0 = o.x * wA.x + o.y * wA.z + o.z * wB.x + o.w * wB.z;
    float c1 = o.x * wA.y + o.y * wA.w + o.z * wB.y + o.w * wB.w;
    c0 = reduce16(c0);   // row_ror stays within the 16-lane slot
    c1 = reduce16(c1);
    if (sl == 0 && act) {
        float2 r; r.x = c0 + bo[0]; r.y = c1 + bo[1];
        outp[node] = r;
    }
}

extern "C" void kernel_launch(void* const* d_in, const int* in_sizes, int n_in,
                              void* d_out, int out_size, void* d_ws, size_t ws_size,
                              hipStream_t stream) {
    const float* feature  = (const float*)d_in[0];
    const int*   src      = (const int*)d_in[1];
    const int*   dst      = (const int*)d_in[2];
    const float* W_in     = (const float*)d_in[3];
    const float* b_in     = (const float*)d_in[4];
    const float* fc_src_W = (const float*)d_in[5];
    const float* fc_src_b = (const float*)d_in[6];
    const float* fc_dst_W = (const float*)d_in[7];
    const float* fc_dst_b = (const float*)d_in[8];
    const float* attn     = (const float*)d_in[9];
    const float* W_out    = (const float*)d_in[10];
    const float* b_out    = (const float*)d_in[11];

    const int N  = in_sizes[0] / 128;      // 50000
    const int E  = in_sizes[1];            // 800000
    const int B1 = (E + 4095) / 4096;      // 196 coarse blocks
    const int NB = (N + 255) / 256;        // 196 coarse buckets (dst>>8)

    char* ws = (char*)d_ws;
    size_t off = 0;
    auto take = [&](size_t bytes) { char* p = ws + off; off = (off + bytes + 255) & ~(size_t)255; return p; };
    int*    counts_T   = (int*)take((size_t)NB * B1 * 4);
    int*    off_T      = (int*)take((size_t)NB * B1 * 4);
    int*    Ssum       = (int*)take((size_t)256 * 4);
    int*    row_ptr    = (int*)take((size_t)(N + 1) * 4);
    int*    karr       = (int*)take((size_t)E * 4);
    int*    edge_src   = (int*)take((size_t)(E + 64) * 4);
    __half* fd         = (__half*)take((size_t)N * 64 * 2);  // layer-0 fd (fp16)
    __half* fd1        = (__half*)take((size_t)N * 64 * 2);  // layer-1 fd (fp16)
    __half* fs_h       = (__half*)take((size_t)N * 64 * 2);  // layer-0 fs
    __half* fs1        = (__half*)take((size_t)N * 64 * 2);  // layer-1 fs
    __half* wq         = (__half*)take((size_t)32768 * 2);   // fused L0 weights hi/lo
    __half* wq1        = (__half*)take((size_t)16384 * 2);   // L1 weights hi/lo
    float*  bf0        = (float*)take((size_t)128 * 4);      // fused L0 biases
    (void)ws_size; (void)n_in; (void)out_size;

    const int gemm_blocks = (N + 63) / 64;    // 782 (64 nodes/block)
    const int g_scan      = (NB + 3) / 4;     // 49 blocks = 196 scan waves
    const int agg_blocks  = (N + 15) / 16;    // 3125 (16 nodes/block, 1/slot)

    // D0: weight prep (fused layer-0 weights; fp16 hi/lo, coalesced layout)
    k_prep<<<193, 128, 0, stream>>>(W_in, b_in,
                                    fc_src_W, fc_src_b, fc_dst_W, fc_dst_b,
                                    fc_src_W + 4096, fc_dst_W + 4096,
                                    wq, wq1, bf0);

    // D1: hist || MFMA fs0/fd0 (K=128 fused, coalesced B loads; fd fp16)
    k_p1_fused<<<B1 + gemm_blocks, 256, 0, stream>>>(
        dst, counts_T, E, B1, NB,
        feature, wq, bf0, fs_h, fd, N, gemm_blocks);

    // D2: parallel coarse scan
    k_scan<<<g_scan, 256, 0, stream>>>(counts_T, off_T, Ssum, row_ptr,
                                       edge_src, E, B1, NB, N);

    // D3: partition edges into coarse buckets (packed 24-bit records)
    k_p3<<<B1, 256, 0, stream>>>(src, dst, off_T, Ssum, karr, E, B1, NB);

    // D4: fine counting sort (512 thr) within buckets -> row_ptr + edge_src
    k_p4<<<NB, 512, 0, stream>>>(karr, Ssum, row_ptr, edge_src, N, NB);

    // D5: layer-0 aggregate (degree-ranked slots) + layer-1 MFMA
    k_agg0_fsfd<<<gemm_blocks, 512, 0, stream>>>(
        fs_h, (const uint2*)fd, (const float4*)attn,
        row_ptr, edge_src, wq1, fc_src_b + 64, fc_dst_b + 64,
        fs1, fd1, N);

    // D7: layer-1 aggregate (degree-ranked slots) + output projection
    k_agg_out<<<agg_blocks, 256, 0, stream>>>(
        fs_h ? fs1 : fs1, (const uint2*)fd1, (const float4*)attn + 16,
        row_ptr, edge_src, (const float4*)W_out, b_out, (float2*)d_out, N);
}

// Round 14
// 186.769 us; speedup vs baseline: 1.0209x; 1.0209x over previous
//
#include <hip/hip_runtime.h>
#include <hip/hip_fp16.h>

#define LRELU_SLOPE 0.2f

typedef _Float16 f16x8 __attribute__((ext_vector_type(8)));
typedef _Float16 f16x2 __attribute__((ext_vector_type(2)));
typedef float    f32x4 __attribute__((ext_vector_type(4)));

// ---------------- DPP helpers ----------------
template <int CTRL>
__device__ __forceinline__ float dpp_add(float x) {
    int xi = __float_as_int(x);
    int yi = __builtin_amdgcn_update_dpp(xi, xi, CTRL, 0xF, 0xF, false);
    return x + __int_as_float(yi);
}
__device__ __forceinline__ float reduce16(float t) {
    t = dpp_add<0x128>(t);  // row_ror:8  (row = 16 lanes)
    t = dpp_add<0x124>(t);  // row_ror:4
    t = dpp_add<0x122>(t);  // row_ror:2
    t = dpp_add<0x121>(t);  // row_ror:1
    return t;
}
__device__ __forceinline__ float reduce_quad(float t) {
    t = dpp_add<0xB1>(t);   // quad_perm [1,0,3,2]
    t = dpp_add<0x4E>(t);   // quad_perm [2,3,0,1]
    return t;
}

__device__ __forceinline__ f16x2 u32_to_h2(unsigned u) {
    union { unsigned u; f16x2 h; } cv; cv.u = u; return cv.h;
}

// ---------------- block-wide exclusive scan (NW waves) ----------------------
template <int NW>
__device__ __forceinline__ int block_excl_scan_t(int v) {
    __shared__ int wsum[NW];
    int tid = threadIdx.x;
    int lane = tid & 63;
    int wid  = tid >> 6;
    int x = v;
#pragma unroll
    for (int off = 1; off < 64; off <<= 1) {
        int y = __shfl_up(x, off, 64);
        if (lane >= off) x += y;
    }
    if (lane == 63) wsum[wid] = x;
    __syncthreads();
    int wofs = 0;
#pragma unroll
    for (int i = 0; i < NW; ++i)
        if (i < wid) wofs += wsum[i];
    return wofs + x - v;  // exclusive
}

// role split for fused kernels: interleave A/B blocks by parity
__device__ __forceinline__ void role_split(int bid, int gA, int gB, bool& isA, int& idx) {
    int m = (gA < gB ? gA : gB) * 2;
    if (bid < m) { isA = (bid & 1) == 0; idx = bid >> 1; }
    else         { isA = (gA > gB);      idx = (m >> 1) + (bid - m); }
}

// ---------------- D0: weight prep ----------------
// Fused L0 weights (Win@Ws0 / Win@Wd0) and L1 weights, fp16 hi/lo Markidis
// split, stored in MFMA-fragment-coalesced layout:
//   addr(m2,t2,ks,lk,lr,e) = group(m2,t2,ks)*512 + lk*128 + lr*8 + e
// wq : [part(2)][32 groups][512]  halfs (64 KB), groups = (m2*4+t2)*4+ks (K=128)
// wq1: [part(2)][16 groups][512]  halfs (32 KB), groups = (m2*4+t2)*2+ks (K=64)
// bf0: fused layer-0 biases: [0..63]=bin@Ws0+bs0, [64..127]=bin@Wd0+bd0
__global__ __launch_bounds__(128) void k_prep(
        const float* __restrict__ Win, const float* __restrict__ bin,
        const float* __restrict__ Ws0, const float* __restrict__ bs0,
        const float* __restrict__ Wd0, const float* __restrict__ bd0,
        const float* __restrict__ Ws1, const float* __restrict__ Wd1,
        __half* __restrict__ wq, __half* __restrict__ wq1,
        float* __restrict__ bf0) {
    _Float16* w0 = (_Float16*)wq;
    _Float16* w1 = (_Float16*)wq1;
    int b = blockIdx.x, t = threadIdx.x;
    int m = t >> 6;      // 0 = src-mat, 1 = dst-mat
    int c = t & 63;      // output column
    int t2 = c >> 4, lr = c & 15;
    if (b < 128) {       // fused layer-0, k-row = b
        const float* W0 = m ? Wd0 : Ws0;
        float s = 0.f;
#pragma unroll 8
        for (int k = 0; k < 64; ++k) s = fmaf(Win[b * 64 + k], W0[k * 64 + c], s);
        _Float16 hi = (_Float16)s;
        _Float16 lo = (_Float16)(s - (float)hi);
        int ks = b >> 5, lk = (b >> 3) & 3, e = b & 7;
        int idx = (((m * 4 + t2) * 4 + ks) * 4 + lk) * 128 + lr * 8 + e;
        w0[idx]         = hi;
        w0[16384 + idx] = lo;
    } else if (b < 192) { // layer-1, k-row = b-128
        int r = b - 128;
        const float* W1 = m ? Wd1 : Ws1;
        float v = W1[r * 64 + c];
        _Float16 hi = (_Float16)v;
        _Float16 lo = (_Float16)(v - (float)hi);
        int ks = r >> 5, lk = (r >> 3) & 3, e = r & 7;
        int idx = (((m * 4 + t2) * 2 + ks) * 4 + lk) * 128 + lr * 8 + e;
        w1[idx]        = hi;
        w1[8192 + idx] = lo;
    } else {              // b == 192: fused biases
        const float* W0 = m ? Wd0 : Ws0;
        const float* b0 = m ? bd0 : bs0;
        float s = b0[c];
#pragma unroll 8
        for (int k = 0; k < 64; ++k) s = fmaf(bin[k], W0[k * 64 + c], s);
        bf0[m * 64 + c] = s;
    }
}

// ---------------- D1: histogram only (196 blocks, ~8us) ----------------------
// GEMM moved to D3 (pairs with p3's LDS-atomic scatter) so the sort chain
// (scan/p3/p4) no longer serializes behind the ~28us MFMA projection.
__global__ __launch_bounds__(256) void k_hist(
        const int* __restrict__ dst, int* __restrict__ counts_T, int E, int B1, int NB) {
    __shared__ int hist[256];
    hist[threadIdx.x] = 0;
    __syncthreads();
    int idx = blockIdx.x;
    int base = idx * 4096;
    if (base + 4096 <= E) {
        const int4* d4 = (const int4*)(dst + base);
#pragma unroll
        for (int it = 0; it < 4; ++it) {
            int4 q = d4[it * 256 + threadIdx.x];
            atomicAdd(&hist[q.x >> 8], 1);
            atomicAdd(&hist[q.y >> 8], 1);
            atomicAdd(&hist[q.z >> 8], 1);
            atomicAdd(&hist[q.w >> 8], 1);
        }
    } else {
        for (int it = 0; it < 16; ++it) {
            int e = base + it * 256 + threadIdx.x;
            if (e < E) atomicAdd(&hist[dst[e] >> 8], 1);
        }
    }
    __syncthreads();
    if (threadIdx.x < NB) counts_T[threadIdx.x * B1 + idx] = hist[threadIdx.x];
}

// ---------------- D2: parallel coarse scan ----------------
__global__ __launch_bounds__(256) void k_scan(
        const int* __restrict__ counts_T, int* __restrict__ off_T,
        int* __restrict__ Ssum, int* __restrict__ row_ptr,
        int* __restrict__ edge_src, int E, int B1, int NB, int n_nodes) {
    int c = blockIdx.x * 4 + (threadIdx.x >> 6);
    int lane = threadIdx.x & 63;
    if (c < NB) {
        int carry = 0;
        for (int b0 = 0; b0 < B1; b0 += 64) {
            int b = b0 + lane;
            int v = (b < B1) ? counts_T[c * B1 + b] : 0;
            int x = v;
#pragma unroll
            for (int o = 1; o < 64; o <<= 1) {
                int y = __shfl_up(x, o, 64);
                if (lane >= o) x += y;
            }
            if (b < B1) off_T[c * B1 + b] = carry + x - v;
            carry += __shfl(x, 63, 64);
        }
        if (lane == 0) Ssum[c] = carry;
    }
    if (blockIdx.x == 0) {
        if (threadIdx.x < 64) edge_src[E + threadIdx.x] = 0;  // pad for k_agg
        if (threadIdx.x == 0) row_ptr[n_nodes] = E;
    }
}

// ---------------- D3: coarse partition || MFMA fs0/fd0 (role split) ----------
// p3 role: LDS-atomic scatter of 800k edges into coarse buckets.
// gemm role: K=128 split-fp16 MFMA projection feat -> fs_h/fd (independent of
// p3's data; complementary pipes -> overlap on the machine).
__global__ __launch_bounds__(256) void k_p3_gemm(
        const int* __restrict__ src, const int* __restrict__ dst,
        const int* __restrict__ off_T, const int* __restrict__ Ssum,
        int* __restrict__ karr, int E, int B1, int NB,
        const float* __restrict__ feat,
        const __half* __restrict__ wq, const float* __restrict__ bf0,
        __half* __restrict__ fs_h, __half* __restrict__ fd, int n, int g_gemm) {
    bool isA; int idx;
    role_split(blockIdx.x, B1, g_gemm, isA, idx);
    if (isA) {
        __shared__ int cur[256];
        int b = idx, t = threadIdx.x;
        int v = (t < NB) ? Ssum[t] : 0;
        int base_t = block_excl_scan_t<4>(v);   // bucket_base[t]
        cur[t] = (t < NB) ? base_t + off_T[t * B1 + b] : 0;
        __syncthreads();
        int base = b * 4096;
        if (base + 4096 <= E) {
            const int4* d4 = (const int4*)(dst + base);
            const int4* s4 = (const int4*)(src + base);
#pragma unroll
            for (int it = 0; it < 4; ++it) {
                int4 qd = d4[it * 256 + t];
                int4 qs = s4[it * 256 + t];
                int pos;
                pos = atomicAdd(&cur[qd.x >> 8], 1); karr[pos] = (qs.x << 8) | (qd.x & 255);
                pos = atomicAdd(&cur[qd.y >> 8], 1); karr[pos] = (qs.y << 8) | (qd.y & 255);
                pos = atomicAdd(&cur[qd.z >> 8], 1); karr[pos] = (qs.z << 8) | (qd.z & 255);
                pos = atomicAdd(&cur[qd.w >> 8], 1); karr[pos] = (qs.w << 8) | (qd.w & 255);
            }
        } else {
            for (int it = 0; it < 16; ++it) {
                int e = base + it * 256 + t;
                if (e < E) {
                    int d = dst[e], s = src[e];
                    int pos = atomicAdd(&cur[d >> 8], 1);  // LDS atomic
                    karr[pos] = (s << 8) | (d & 255);
                }
            }
        }
        return;
    }
    // ---- gemm role: fs0/fd0 projection (fused weights, K=128) ----
    const _Float16* w = (const _Float16*)wq;
    int node0 = idx * 64;
    int wv   = threadIdx.x >> 6;
    int lane = threadIdx.x & 63;
    int lr = lane & 15;   // A-row / B-col in tile
    int lk = lane >> 4;   // k-chunk selector
    int lofs = lk * 128 + lr * 8;   // lane offset within B fragment group
    int arow = node0 + wv * 16 + lr;
    int arc  = arow < n ? arow : n - 1;
    const float* fp = feat + (size_t)arc * 128 + lk * 8;
    f32x4 zero = {0.f, 0.f, 0.f, 0.f};
    f32x4 acc[2][4];
#pragma unroll
    for (int m2 = 0; m2 < 2; ++m2)
#pragma unroll
        for (int t2 = 0; t2 < 4; ++t2) acc[m2][t2] = zero;
#pragma unroll
    for (int ks = 0; ks < 4; ++ks) {   // K = 128, 32 per step
        float4 a0 = *(const float4*)(fp + ks * 32);
        float4 a1 = *(const float4*)(fp + ks * 32 + 4);
        float av[8] = {a0.x, a0.y, a0.z, a0.w, a1.x, a1.y, a1.z, a1.w};
        f16x8 ahi, alo;
#pragma unroll
        for (int i = 0; i < 8; ++i) {
            _Float16 hh = (_Float16)av[i];
            ahi[i] = hh;
            alo[i] = (_Float16)(av[i] - (float)hh);
        }
#pragma unroll
        for (int m2 = 0; m2 < 2; ++m2) {
#pragma unroll
            for (int t2 = 0; t2 < 4; ++t2) {
                const _Float16* wb = w + ((m2 * 4 + t2) * 4 + ks) * 512 + lofs;
                f16x8 bhi = *(const f16x8*)(wb);
                f16x8 blo = *(const f16x8*)(wb + 16384);
                acc[m2][t2] = __builtin_amdgcn_mfma_f32_16x16x32_f16(ahi, bhi, acc[m2][t2], 0, 0, 0);
                acc[m2][t2] = __builtin_amdgcn_mfma_f32_16x16x32_f16(alo, bhi, acc[m2][t2], 0, 0, 0);
                acc[m2][t2] = __builtin_amdgcn_mfma_f32_16x16x32_f16(ahi, blo, acc[m2][t2], 0, 0, 0);
            }
        }
    }
    int obase = node0 + wv * 16 + lk * 4;   // D row = (lane>>4)*4 + reg
#pragma unroll
    for (int t2 = 0; t2 < 4; ++t2) {
        int col = t2 * 16 + lr;
        float bs = bf0[col];
        float bd = bf0[64 + col];
#pragma unroll
        for (int r = 0; r < 4; ++r) {
            int nd = obase + r;
            if (nd < n) {
                fs_h[(size_t)nd * 64 + col] = __float2half(acc[0][t2][r] + bs);
                fd[(size_t)nd * 64 + col]   = __float2half(acc[1][t2][r] + bd);
            }
        }
    }
}

// ---------------- D4: fine counting sort (512 thr), single global pass -------
__global__ __launch_bounds__(512) void k_p4(
        const int* __restrict__ karr, const int* __restrict__ Ssum,
        int* __restrict__ row_ptr, int* __restrict__ edge_src, int n, int NB) {
    __shared__ int sb[257];
    __shared__ int cnt[256];
    __shared__ int curv[256];
    __shared__ int ebuf[8192];   // 32KB: bucket mean 4096, std ~64
    int c = blockIdx.x, t = threadIdx.x;
    int v = (t < NB) ? Ssum[t] : 0;
    int excl = block_excl_scan_t<8>(v);
    if (t < 256) {
        sb[t] = excl;
        if (t == 255) sb[256] = excl + v;
        cnt[t] = 0;
    }
    __syncthreads();
    int lo = sb[c], hi = sb[c + 1];
    int ec = hi - lo;
    int nbuf = ec < 8192 ? ec : 8192;
    for (int i = t; i < nbuf; i += 512) {
        int p = karr[lo + i];
        ebuf[i] = p;
        atomicAdd(&cnt[p & 255], 1);
    }
    for (int i = 8192 + t; i < ec; i += 512)      // overflow path (theoretical)
        atomicAdd(&cnt[karr[lo + i] & 255], 1);
    __syncthreads();
    int v2 = (t < 256) ? cnt[t] : 0;
    int excl2 = block_excl_scan_t<8>(v2);
    if (t < 256) {
        int node = c * 256 + t;
        if (node < n) row_ptr[node] = lo + excl2;
        curv[t] = lo + excl2;
    }
    __syncthreads();
    for (int i = t; i < nbuf; i += 512) {
        int p = ebuf[i];
        int pos = atomicAdd(&curv[p & 255], 1);   // LDS atomic
        edge_src[pos] = p >> 8;                    // top bits 0 (24-bit pack)
    }
    for (int i = 8192 + t; i < ec; i += 512) {
        int p = karr[lo + i];
        int pos = atomicAdd(&curv[p & 255], 1);
        edge_src[pos] = p >> 8;
    }
}

// ---------------- GATv2 aggregate common (packed fp16 edge math) -------------
__device__ __forceinline__ void edge_accum_pk(
        uint2 raw, f16x2 fd01, f16x2 fd23, f16x2 a01, f16x2 a23,
        f16x2 slope2, bool valid, float& ssum, float4& acc) {
    f16x2 h01 = u32_to_h2(raw.x);
    f16x2 h23 = u32_to_h2(raw.y);
    f16x2 t01 = h01 + fd01;
    f16x2 t23 = h23 + fd23;
    f16x2 l01 = __builtin_elementwise_max(t01, t01 * slope2);
    f16x2 l23 = __builtin_elementwise_max(t23, t23 * slope2);
    f16x2 s2  = l01 * a01 + l23 * a23;
    float s = (float)s2[0] + (float)s2[1];
    s = reduce_quad(s);
    float p = valid ? __expf(s) : 0.f;
    ssum += p;
    acc.x = fmaf(p, (float)h01[0], acc.x);
    acc.y = fmaf(p, (float)h01[1], acc.y);
    acc.z = fmaf(p, (float)h23[0], acc.z);
    acc.w = fmaf(p, (float)h23[1], acc.w);
}

// Software-pipelined gather-aggregate for one 16-lane slot over [s0,s1).
__device__ __forceinline__ void gather_run(
        const __half* __restrict__ fs_h, const int* __restrict__ edge_src,
        f16x2 a01, f16x2 a23, f16x2 fd01, f16x2 fd23, f16x2 slope2,
        int sl, int s0, int s1, float& ssum, float4& acc) {
    if (s0 >= s1) return;
    int id[8];
#pragma unroll
    for (int j = 0; j < 8; ++j)
        id[j] = edge_src[s0 + j];                    // pad past E is zeroed
    for (int e = s0; e < s1; e += 8) {
        uint2 raw[8];
#pragma unroll
        for (int j = 0; j < 8; ++j)
            raw[j] = *(const uint2*)(fs_h + (size_t)(unsigned)id[j] * 64 + sl * 4);
        int idn[8];
#pragma unroll
        for (int j = 0; j < 8; ++j)
            idn[j] = edge_src[e + 8 + j];            // prefetch next batch (pad-safe)
#pragma unroll
        for (int j = 0; j < 8; ++j)
            edge_accum_pk(raw[j], fd01, fd23, a01, a23, slope2,
                          e + j < s1, ssum, acc);
#pragma unroll
        for (int j = 0; j < 8; ++j) id[j] = idn[j];
    }
}

// ---------------- D5: layer-0 aggregate + layer-1 fs/fd MFMA (fused) ---------
// 512 threads. Phase A: 32 slots x 2 rounds gather-aggregate 64 nodes with
// degree-rank slot assignment. Phase B: 8 waves run layer-1 projections from
// LDS via split-fp16 MFMA. L1 outputs to separate buffers (fs1/fd1).
__global__ __launch_bounds__(512) void k_agg0_fsfd(
        const __half* __restrict__ fs_h, const uint2* __restrict__ fdh,
        const float4* __restrict__ attn4,
        const int* __restrict__ row_ptr, const int* __restrict__ edge_src,
        const __half* __restrict__ wq1,
        const float* __restrict__ bs, const float* __restrict__ bd,
        __half* __restrict__ fs1, __half* __restrict__ fd1, int n) {
    __shared__ float HL[64 * 68];
    __shared__ int dcnt[64];
    __shared__ int perm[64];
    int tid  = threadIdx.x;
    int lane = tid & 63;
    int w    = tid >> 6;        // wave 0..7
    int slot = tid >> 4;        // 0..31
    int sl   = tid & 15;
    int node0 = blockIdx.x * 64;
    if (tid < 64) {
        int node = node0 + tid;
        int cnt = 0;
        if (node < n) cnt = row_ptr[node + 1] - row_ptr[node];
        dcnt[tid] = cnt;
    }
    __syncthreads();
    if (tid < 64) {
        int mc = dcnt[tid];
        int rank = 0;
#pragma unroll 8
        for (int j = 0; j < 64; ++j) {
            int cj = dcnt[j];
            rank += ((cj > mc) || (cj == mc && j < tid)) ? 1 : 0;
        }
        perm[rank] = tid;
    }
    __syncthreads();
    float4 a4 = attn4[sl];
    f16x2 a01 = { (_Float16)a4.x, (_Float16)a4.y };
    f16x2 a23 = { (_Float16)a4.z, (_Float16)a4.w };
    f16x2 slope2 = { (_Float16)LRELU_SLOPE, (_Float16)LRELU_SLOPE };
#pragma unroll
    for (int r = 0; r < 2; ++r) {
        int li = perm[r * 32 + slot];   // degree-rank -> local node
        int node = node0 + li;
        bool act = node < n;
        int nd = act ? node : 0;
        uint2 fdr = fdh[(size_t)nd * 16 + sl];
        f16x2 fd01 = u32_to_h2(fdr.x);
        f16x2 fd23 = u32_to_h2(fdr.y);
        int s0 = row_ptr[nd];
        int s1 = act ? row_ptr[nd + 1] : s0;
        float4 acc = {0.f, 0.f, 0.f, 0.f};
        float ssum = 0.f;
        gather_run(fs_h, edge_src, a01, a23, fd01, fd23, slope2,
                   sl, s0, s1, ssum, acc);
        float inv = (s1 > s0) ? 1.f / ssum : 0.f;
        float4 o;
        o.x = fmaxf(acc.x * inv, 0.f);
        o.y = fmaxf(acc.y * inv, 0.f);
        o.z = fmaxf(acc.z * inv, 0.f);
        o.w = fmaxf(acc.w * inv, 0.f);               // inactive rows -> zeros
        *(float4*)(HL + li * 68 + sl * 4) = o;
    }
    __syncthreads();
    // ---- Phase B: layer-1 fs/fd GEMM from LDS h-tile ----
    const _Float16* wp = (const _Float16*)wq1;
    int lr = lane & 15;
    int lk = lane >> 4;
    int rg = (w & 3) * 16;      // row group
    int m2 = w >> 2;            // 0 = fs, 1 = fd
    int lofs = lk * 128 + lr * 8;
    f32x4 zero = {0.f, 0.f, 0.f, 0.f};
    f32x4 acc2[4];
#pragma unroll
    for (int t2 = 0; t2 < 4; ++t2) acc2[t2] = zero;
#pragma unroll
    for (int ks = 0; ks < 2; ++ks) {   // K = 64
        const float* hp = HL + (rg + lr) * 68 + ks * 32 + lk * 8;
        float4 a0v = *(const float4*)(hp);
        float4 a1v = *(const float4*)(hp + 4);
        float av[8] = {a0v.x, a0v.y, a0v.z, a0v.w, a1v.x, a1v.y, a1v.z, a1v.w};
        f16x8 ahi, alo;
#pragma unroll
        for (int i = 0; i < 8; ++i) {
            _Float16 hh = (_Float16)av[i];
            ahi[i] = hh;
            alo[i] = (_Float16)(av[i] - (float)hh);
        }
#pragma unroll
        for (int t2 = 0; t2 < 4; ++t2) {
            const _Float16* wb = wp + ((m2 * 4 + t2) * 2 + ks) * 512 + lofs;
            f16x8 bhi = *(const f16x8*)(wb);
            f16x8 blo = *(const f16x8*)(wb + 8192);
            acc2[t2] = __builtin_amdgcn_mfma_f32_16x16x32_f16(ahi, bhi, acc2[t2], 0, 0, 0);
            acc2[t2] = __builtin_amdgcn_mfma_f32_16x16x32_f16(alo, bhi, acc2[t2], 0, 0, 0);
            acc2[t2] = __builtin_amdgcn_mfma_f32_16x16x32_f16(ahi, blo, acc2[t2], 0, 0, 0);
        }
    }
    const float* bp = m2 ? bd : bs;
    int obase = node0 + rg + lk * 4;
#pragma unroll
    for (int t2 = 0; t2 < 4; ++t2) {
        int col = t2 * 16 + lr;
        float bv = bp[col];
#pragma unroll
        for (int r = 0; r < 4; ++r) {
            int nd = obase + r;
            if (nd < n) {
                if (m2 == 0)
                    fs1[(size_t)nd * 64 + col] = __float2half(acc2[t2][r] + bv);
                else
                    fd1[(size_t)nd * 64 + col] = __float2half(acc2[t2][r] + bv);
            }
        }
    }
}

// ---------------- D7: layer-1 aggregate + output projection ------------------
// 256 threads, 16 nodes, degree-rank slot assignment.
__global__ __launch_bounds__(256) void k_agg_out(
        const __half* __restrict__ fs_h, const uint2* __restrict__ fdh,
        const float4* __restrict__ attn4,
        const int* __restrict__ row_ptr, const int* __restrict__ edge_src,
        const float4* __restrict__ Wo4,
        const float* __restrict__ bo, float2* __restrict__ outp, int n) {
    __shared__ int dcnt[16];
    __shared__ int perm16[16];
    int t    = threadIdx.x;
    int lane = t & 63;
    int wid  = t >> 6;
    int slot = lane >> 4;
    int sl   = lane & 15;
    int node0 = blockIdx.x * 16;
    if (t < 16) {
        int node = node0 + t;
        int cnt = 0;
        if (node < n) cnt = row_ptr[node + 1] - row_ptr[node];
        dcnt[t] = cnt;
    }
    __syncthreads();
    if (t < 16) {
        int mc = dcnt[t];
        int rank = 0;
#pragma unroll
        for (int j = 0; j < 16; ++j)
            rank += ((dcnt[j] > mc) || (dcnt[j] == mc && j < t)) ? 1 : 0;
        perm16[rank] = t;
    }
    __syncthreads();
    int li = perm16[wid * 4 + slot];   // degree-rank -> local node
    int node = node0 + li;
    bool act = node < n;
    int nd = act ? node : 0;
    float4 a4  = attn4[sl];
    f16x2 a01 = { (_Float16)a4.x, (_Float16)a4.y };
    f16x2 a23 = { (_Float16)a4.z, (_Float16)a4.w };
    f16x2 slope2 = { (_Float16)LRELU_SLOPE, (_Float16)LRELU_SLOPE };
    uint2 fdr = fdh[(size_t)nd * 16 + sl];
    f16x2 fd01 = u32_to_h2(fdr.x);
    f16x2 fd23 = u32_to_h2(fdr.y);
    int s0 = row_ptr[nd];
    int s1 = act ? row_ptr[nd + 1] : s0;
    float4 acc = {0.f, 0.f, 0.f, 0.f};
    float ssum = 0.f;
    gather_run(fs_h, edge_src, a01, a23, fd01, fd23, slope2,
               sl, s0, s1, ssum, acc);
    float inv = (s1 > s0) ? 1.f / ssum : 0.f;
    float4 o;
    o.x = fmaxf(acc.x * inv, 0.f);
    o.y = fmaxf(acc.y * inv, 0.f);
    o.z = fmaxf(acc.z * inv, 0.f);
    o.w = fmaxf(acc.w * inv, 0.f);
    float4 wA = Wo4[sl * 2 + 0];
    float4 wB = Wo4[sl * 2 + 1];
    float c0 = o.x * wA.x + o.y * wA.z + o.z * wB.x + o.w * wB.z;
    float c1 = o.x * wA.y + o.y * wA.w + o.z * wB.y + o.w * wB.w;
    c0 = reduce16(c0);   // row_ror stays within the 16-lane slot
    c1 = reduce16(c1);
    if (sl == 0 && act) {
        float2 r; r.x = c0 + bo[0]; r.y = c1 + bo[1];
        outp[node] = r;
    }
}

extern "C" void kernel_launch(void* const* d_in, const int* in_sizes, int n_in,
                              void* d_out, int out_size, void* d_ws, size_t ws_size,
                              hipStream_t stream) {
    const float* feature  = (const float*)d_in[0];
    const int*   src      = (const int*)d_in[1];
    const int*   dst      = (const int*)d_in[2];
    const float* W_in     = (const float*)d_in[3];
    const float* b_in     = (const float*)d_in[4];
    const float* fc_src_W = (const float*)d_in[5];
    const float* fc_src_b = (const float*)d_in[6];
    const float* fc_dst_W = (const float*)d_in[7];
    const float* fc_dst_b = (const float*)d_in[8];
    const float* attn     = (const float*)d_in[9];
    const float* W_out    = (const float*)d_in[10];
    const float* b_out    = (const float*)d_in[11];

    const int N  = in_sizes[0] / 128;      // 50000
    const int E  = in_sizes[1];            // 800000
    const int B1 = (E + 4095) / 4096;      // 196 coarse blocks
    const int NB = (N + 255) / 256;        // 196 coarse buckets (dst>>8)

    char* ws = (char*)d_ws;
    size_t off = 0;
    auto take = [&](size_t bytes) { char* p = ws + off; off = (off + bytes + 255) & ~(size_t)255; return p; };
    int*    counts_T   = (int*)take((size_t)NB * B1 * 4);
    int*    off_T      = (int*)take((size_t)NB * B1 * 4);
    int*    Ssum       = (int*)take((size_t)256 * 4);
    int*    row_ptr    = (int*)take((size_t)(N + 1) * 4);
    int*    karr       = (int*)take((size_t)E * 4);
    int*    edge_src   = (int*)take((size_t)(E + 64) * 4);
    __half* fd         = (__half*)take((size_t)N * 64 * 2);  // layer-0 fd (fp16)
    __half* fd1        = (__half*)take((size_t)N * 64 * 2);  // layer-1 fd (fp16)
    __half* fs_h       = (__half*)take((size_t)N * 64 * 2);  // layer-0 fs
    __half* fs1        = (__half*)take((size_t)N * 64 * 2);  // layer-1 fs
    __half* wq         = (__half*)take((size_t)32768 * 2);   // fused L0 weights hi/lo
    __half* wq1        = (__half*)take((size_t)16384 * 2);   // L1 weights hi/lo
    float*  bf0        = (float*)take((size_t)128 * 4);      // fused L0 biases
    (void)ws_size; (void)n_in; (void)out_size;

    const int gemm_blocks = (N + 63) / 64;    // 782 (64 nodes/block)
    const int g_scan      = (NB + 3) / 4;     // 49 blocks = 196 scan waves
    const int agg_blocks  = (N + 15) / 16;    // 3125 (16 nodes/block, 1/slot)

    // D0: weight prep (fused layer-0 weights; fp16 hi/lo, coalesced layout)
    k_prep<<<193, 128, 0, stream>>>(W_in, b_in,
                                    fc_src_W, fc_src_b, fc_dst_W, fc_dst_b,
                                    fc_src_W + 4096, fc_dst_W + 4096,
                                    wq, wq1, bf0);

    // D1: histogram only (sort chain no longer waits on the GEMM)
    k_hist<<<B1, 256, 0, stream>>>(dst, counts_T, E, B1, NB);

    // D2: parallel coarse scan
    k_scan<<<g_scan, 256, 0, stream>>>(counts_T, off_T, Ssum, row_ptr,
                                       edge_src, E, B1, NB, N);

    // D3: coarse partition || MFMA fs0/fd0 (overlapped roles)
    k_p3_gemm<<<B1 + gemm_blocks, 256, 0, stream>>>(
        src, dst, off_T, Ssum, karr, E, B1, NB,
        feature, wq, bf0, fs_h, fd, N, gemm_blocks);

    // D4: fine counting sort (512 thr) within buckets -> row_ptr + edge_src
    k_p4<<<NB, 512, 0, stream>>>(karr, Ssum, row_ptr, edge_src, N, NB);

    // D5: layer-0 aggregate (degree-ranked slots) + layer-1 MFMA
    k_agg0_fsfd<<<gemm_blocks, 512, 0, stream>>>(
        fs_h, (const uint2*)fd, (const float4*)attn,
        row_ptr, edge_src, wq1, fc_src_b + 64, fc_dst_b + 64,
        fs1, fd1, N);

    // D7: layer-1 aggregate (degree-ranked slots) + output projection
    k_agg_out<<<agg_blocks, 256, 0, stream>>>(
        fs1, (const uint2*)fd1, (const float4*)attn + 16,
        row_ptr, edge_src, (const float4*)W_out, b_out, (float2*)d_out, N);
}